// Round 6
// baseline (190.690 us; speedup 1.0000x reference)
//
#include <hip/hip_runtime.h>
#include <stdint.h>

typedef unsigned long long u64;
typedef unsigned int u32;
typedef unsigned short u16;

#define NN 2048
#define NW 32    // u64 words per 2048-bit row

#if __has_builtin(__builtin_amdgcn_sbfe)
#define SBFE(x, o) ((u32)__builtin_amdgcn_sbfe((int)(x), (u32)(o), 1u))
#else
#define SBFE(x, o) ((u32)(-(int)(((x) >> (o)) & 1u)))
#endif

static __device__ __forceinline__ bool gumbel_gt(float x, float g0, float g1) {
    // jax.nn.log_sigmoid(x) = -(max(-x,0) + log1p(exp(-|x|)))
    float L = log1pf(expf(-fabsf(x)));
    float a = (-(fmaxf(-x, 0.f) + L)) + g0;   // ye[0]
    float b = (-(fmaxf( x, 0.f) + L)) + g1;   // ye[1]
    return a > b;
}

// acc |= (bit b0 of m ? w0 : 0) | (bit b0+1 of m ? w1 : 0); b0 even, compile-time
static __device__ __forceinline__ u64 orsel2(u64 acc, u64 w0, u64 w1, u64 m, int b0) {
    u32 mm = (b0 < 32) ? (u32)m : (u32)(m >> 32);
    int sh = b0 & 31;
    u32 s0 = SBFE(mm, sh);
    u32 s1 = SBFE(mm, sh + 1);
    u32 al = (u32)acc | ((u32)w0 & s0) | ((u32)w1 & s1);
    u32 ah = (u32)(acc >> 32) | ((u32)(w0 >> 32) & s0) | ((u32)(w1 >> 32) & s1);
    return ((u64)ah << 32) | al;
}

// ---------------------------------------------------------------------------
// K1: hard-edge bitmask  he[i][j]
// ---------------------------------------------------------------------------
__global__ __launch_bounds__(256) void prep_kernel(
    const float* __restrict__ edge_logits,
    const float* __restrict__ g_edge,
    u64* __restrict__ heBits)
{
    const int i = blockIdx.x;
    const int t = threadIdx.x;
    const int lane = t & 63;
    const int wave = t >> 6;
    for (int c = wave; c < NW; c += 4) {
        int j = (c << 6) + lane;
        float x  = edge_logits[(size_t)i * NN + j];
        float g0 = g_edge[(size_t)i * (2 * NN) + j];
        float g1 = g_edge[(size_t)i * (2 * NN) + NN + j];
        u64 m = __ballot(gumbel_gt(x, g0, g1));
        if (lane == 0) heBits[(size_t)i * NW + c] = m;
    }
}

// ---------------------------------------------------------------------------
// K2: level-synchronous BFS order (unchanged — proven).
// ---------------------------------------------------------------------------
__global__ __launch_bounds__(1024) void order_kernel(
    const float* __restrict__ root_logits,
    const float* __restrict__ g_root,
    const u64* __restrict__ heBits,
    u16* __restrict__ posr,
    u16* __restrict__ porderW,
    int* __restrict__ nrPtr)
{
    __shared__ u64 s_root[NW], s_enq[NW], s_F[NW];
    __shared__ u64 s_U[16][NW];
    __shared__ u64 s_Pg[16][NW];
    __shared__ int s_porder[NN];
    __shared__ u16 s_pos[NN];
    __shared__ u16 s_f[NN];
    __shared__ u16 s_rk[NN];
    __shared__ int s_cnt[NN];
    __shared__ int s_wsum[16], s_woff[16];
    __shared__ int s_base, s_lo, s_levcnt, s_newcnt, s_nr;

    const int t    = threadIdx.x;
    const int lane = t & 63;
    const int wid  = t >> 6;
    const int half = lane >> 5;
    const int w    = lane & 31;

    for (int p = 0; p < 2; ++p) {
        int j = p * 1024 + t;
        bool rb = gumbel_gt(root_logits[j], g_root[j], g_root[NN + j]);
        u64 m = __ballot(rb);
        if (lane == 0) s_root[j >> 6] = m;
    }
    __syncthreads();
    for (int p = 0; p < 2; ++p) {
        int j = p * 1024 + t;
        int ww = j >> 6; u64 bit = 1ull << (j & 63);
        if (s_root[ww] & bit) {
            int r = 0;
            for (int k = 0; k < ww; ++k) r += __popcll(s_root[k]);
            r += __popcll(s_root[ww] & (bit - 1ull));
            s_pos[j] = (u16)r;
            s_porder[r] = j;
        }
    }
    if (t < NW) s_enq[t] = s_root[t];
    if (t == 0) {
        int tl = 0;
        for (int k = 0; k < NW; ++k) tl += __popcll(s_root[k]);
        s_lo = 0; s_levcnt = tl; s_base = tl; s_nr = tl;
    }
    __syncthreads();

    while (s_levcnt > 0 && s_base < NN) {
        const int lo = s_lo, cnt = s_levcnt, base = s_base;
        const int seglen = (cnt + 15) >> 4;
        const int s0 = wid * seglen;
        const int s1 = (s0 + seglen < cnt) ? (s0 + seglen) : cnt;

        {
            u64 acc = 0;
            for (int m = s0 + half; m < s1; m += 2)
                acc |= heBits[(size_t)s_porder[lo + m] * NW + w];
            acc |= __shfl(acc, lane ^ 32);
            if (half == 0) s_U[wid][w] = acc;
        }
        __syncthreads();
        if (t < NW) {
            u64 o = 0;
            #pragma unroll
            for (int s = 0; s < 16; ++s) o |= s_U[s][t];
            s_F[t] = o & ~s_enq[t] & ~s_root[t];
        }
        __syncthreads();
        if (t < 512) {
            int s = t >> 5, ww = t & 31;
            u64 p = 0;
            for (int s2 = 0; s2 < s; ++s2) p |= s_U[s2][ww];
            s_Pg[s][ww] = p & s_F[ww];
        }
        __syncthreads();
        {
            u64 P  = s_Pg[wid][w];
            u64 Fw = s_F[w];
            int myidx = (s0 + lane < s1) ? s_porder[lo + s0 + lane] : 0;
            for (int m = s0; m < s1; m += 2) {
                int m0 = m + half;
                int rowi = __shfl(myidx, (m - s0) + half);
                u64 r = 0;
                if (m0 < s1) r = heBits[(size_t)rowi * NW + w];
                u64 v = r & Fw & ~P;
                u64 vlo = __shfl(v, w);
                u64 B = half ? (v & ~vlo) : v;
                int pc = __popcll(B);
                int inc = pc;
                #pragma unroll
                for (int d = 1; d < 32; d <<= 1) {
                    int u2 = __shfl_up(inc, d, 64);
                    if (w >= d) inc += u2;
                }
                int excl = inc - pc;
                int tot = __shfl(inc, (half << 5) | 31);
                if (w == 0 && m0 < s1) s_cnt[m0] = tot;
                u64 mm = B;
                int idx = excl;
                while (mm) {
                    int b = __ffsll(mm) - 1; mm &= mm - 1;
                    int j = (w << 6) + b;
                    s_f[j]  = (u16)m0;
                    s_rk[j] = (u16)idx++;
                }
                P |= B | __shfl(B, lane ^ 32);
            }
        }
        __syncthreads();
        {
            int b0 = 2 * t, b1 = 2 * t + 1;
            int c0 = (b0 < cnt) ? s_cnt[b0] : 0;
            int c1 = (b1 < cnt) ? s_cnt[b1] : 0;
            int pairv = c0 + c1;
            int incl = pairv;
            for (int d = 1; d < 64; d <<= 1) {
                int v = __shfl_up(incl, d, 64);
                if (lane >= d) incl += v;
            }
            if (lane == 63) s_wsum[wid] = incl;
            __syncthreads();
            if (t < 16) {
                int v = s_wsum[t];
                int inc2 = v;
                for (int d = 1; d < 16; d <<= 1) {
                    int u = __shfl_up(inc2, d, 16);
                    if (t >= d) inc2 += u;
                }
                s_woff[t] = inc2 - v;
                if (t == 15) s_newcnt = inc2;
            }
            __syncthreads();
            int excl = s_woff[wid] + (incl - pairv);
            if (b0 < cnt) s_cnt[b0] = excl;
            if (b1 < cnt) s_cnt[b1] = excl + c0;
        }
        __syncthreads();
        for (int p = 0; p < 2; ++p) {
            int j = p * 1024 + t;
            int ww = j >> 6;
            if ((s_F[ww] >> (j & 63)) & 1ull) {
                int slot = base + s_cnt[s_f[j]] + s_rk[j];
                s_pos[j] = (u16)slot;
                s_porder[slot] = j;
            }
        }
        if (t < NW) s_enq[t] |= s_F[t];
        __syncthreads();
        if (t == 0) { s_lo = base; s_levcnt = s_newcnt; s_base = base + s_newcnt; }
        __syncthreads();
    }

    for (int p = 0; p < 2; ++p) {
        int j = p * 1024 + t;
        int ww = j >> 6; u64 bit = 1ull << (j & 63);
        if (!((s_enq[ww] >> (j & 63)) & 1ull)) {
            int rk = 0;
            for (int k2 = 0; k2 < ww; ++k2) rk += __popcll(~s_enq[k2]);
            rk += __popcll(~s_enq[ww] & (bit - 1ull));
            int slot = s_base + rk;
            s_pos[j] = (u16)slot;
            s_porder[slot] = j;
        }
    }
    __syncthreads();
    for (int p = 0; p < 2; ++p) {
        int j = p * 1024 + t;
        int fl = s_pos[j];
        if ((s_root[j >> 6] >> (j & 63)) & 1ull) fl |= 0x8000;
        if ((s_enq[j >> 6]  >> (j & 63)) & 1ull) fl |= 0x4000;
        posr[j] = (u16)fl;
        porderW[j] = (u16)s_porder[j];
    }
    if (t == 0) *nrPtr = s_nr;
}

// ---------------------------------------------------------------------------
// K3: bit-transpose heBits -> heT
// ---------------------------------------------------------------------------
__global__ __launch_bounds__(64) void transpose_kernel(
    const u64* __restrict__ heBits, u64* __restrict__ heT)
{
    const int ti = blockIdx.x >> 5;
    const int tj = blockIdx.x & 31;
    const int r = threadIdx.x;
    u64 w = heBits[(size_t)(64 * ti + r) * NW + tj];
    u64 out = 0;
    #pragma unroll
    for (int b = 0; b < 64; ++b) {
        u64 m = __ballot(((w >> b) & 1ull) != 0);
        if (b == r) out = m;
    }
    heT[(size_t)(64 * tj + r) * NW + ti] = out;
}

// ---------------------------------------------------------------------------
// K4: permuted strict-lower parent matrix
// ---------------------------------------------------------------------------
__global__ __launch_bounds__(256) void apbuild_kernel(
    const u64* __restrict__ heT, const u16* __restrict__ porderW,
    const int* __restrict__ nrPtr, u64* __restrict__ Ap)
{
    __shared__ u64 s_row[NW];
    __shared__ u16 s_inv[NN];
    __shared__ int s_invb, s_nr;
    const int b = blockIdx.x;
    const int t = threadIdx.x;
    for (int q = t; q < NN; q += 256) s_inv[q] = porderW[q];
    if (t == 0) { s_invb = porderW[b]; s_nr = *nrPtr; }
    __syncthreads();
    if (t < NW) s_row[t] = heT[(size_t)s_invb * NW + t];
    __syncthreads();
    const bool bge = (b >= s_nr);
    for (int pass = 0; pass < 8; ++pass) {
        int a = pass * 256 + t;
        int ia = s_inv[a];
        bool bit = bge && (a < b) &&
                   (((s_row[ia >> 6] >> (ia & 63)) & 1ull) != 0);
        u64 m = __ballot(bit);
        if ((t & 63) == 0) Ap[(size_t)b * NW + (a >> 6)] = m;
    }
}

// ---------------------------------------------------------------------------
// K5: diagonal closures Di[k]; ALSO zero-fills M1 and Anc[B,T] (merge outputs)
// ---------------------------------------------------------------------------
__global__ __launch_bounds__(64) void diag_kernel(
    const u64* __restrict__ Ap, u64* __restrict__ Di,
    u64* __restrict__ M1, u64* __restrict__ Anc)
{
    __shared__ u64 sm[64];
    const int r = threadIdx.x;
    const int k = blockIdx.x;
    // zero M1 (1024x16 words) and Anc rows [1024,2048) words [0,16)
    {
        int tid = k * 64 + r;
        for (int q = tid; q < 16384; q += 2048) M1[q] = 0ull;
        for (int q = tid; q < 16384; q += 2048)
            Anc[(size_t)(1024 + (q >> 4)) * NW + (q & 15)] = 0ull;
    }
    u64 M = Ap[(size_t)(64 * k + r) * NW + k] | (1ull << r);
    for (int s = 0; s < 6; ++s) {
        sm[r] = M;
        __syncthreads();
        u64 acc = 0;
        #pragma unroll
        for (int b = 0; b < 64; ++b)
            acc |= sm[b] & (0ull - ((M >> b) & 1ull));
        __syncthreads();
        M = acc;
    }
    Di[64 * k + r] = M;
}

// ---------------------------------------------------------------------------
// K5b: premultiply Ap_ij := Di * Ap_ij for all j < i (incl. cross blocks)
// ---------------------------------------------------------------------------
__global__ __launch_bounds__(64) void ap2_kernel(
    const u64* __restrict__ Di, u64* __restrict__ Ap)
{
    const int i = blockIdx.x;
    const int j = blockIdx.y;
    if (j >= i) return;
    __shared__ u64 sm[64];
    const int r = threadIdx.x;
    u64 d = Di[64 * i + r];
    sm[r] = Ap[(size_t)(64 * i + r) * NW + j];
    __syncthreads();
    u64 acc = 0;
    #pragma unroll
    for (int b = 0; b < 64; ++b)
        acc |= sm[b] & (0ull - ((d >> b) & 1ull));
    Ap[(size_t)(64 * i + r) * NW + j] = acc;
}

// ---------------------------------------------------------------------------
// K6: half-triangle forward-substitution closure.
// grid 32: half h = blk>>4, local col k = blk&15; column kk = 16h + k.
// Computes A* (h=0) and B* (h=1) columns; zeroes rows above the diagonal
// block at word kk (this also clears Anc[T, B-cols]).
// ---------------------------------------------------------------------------
__global__ __launch_bounds__(1024) void colhalf_kernel(
    const u64* __restrict__ Ap, const u64* __restrict__ Di,
    u64* __restrict__ Anc)
{
    __shared__ __align__(16) u64 colA[16][64];   // 8 KB
    __shared__ u64 part[16][64];                 // 8 KB
    const int t  = threadIdx.x;
    const int r  = t & 63;
    const int wv = t >> 6;
    const int k    = blockIdx.x & 15;
    const int hb   = blockIdx.x >> 4;
    const int base = hb << 4;
    const int bend = base + 16;
    const int kk   = base + k;

    for (int row = t; row < 64 * kk; row += 1024)
        Anc[(size_t)row * NW + kk] = 0ull;

    if (t < 64) {
        u64 d = Di[64 * kk + r];
        colA[0][r] = d;
        Anc[(size_t)(64 * kk + r) * NW + kk] = d;
    }
    __syncthreads();

    const int j0 = kk + wv;   // 16 waves cover all j in [kk, kk+15]

    for (int ib = kk + 1; ib < bend; ib += 4) {
        u64 m0[4], acc[4];
        #pragma unroll
        for (int g = 0; g < 4; ++g) {
            int ig = ib + g;
            bool v = (ig < bend);
            m0[g] = (v && (j0 < ib)) ? Ap[(size_t)(64 * ig + r) * NW + j0] : 0ull;
            acc[g] = 0ull;
        }
        u64 tm[3][3];
        #pragma unroll
        for (int s = 0; s < 3; ++s) {
            #pragma unroll
            for (int q = 0; q < 3; ++q) {
                int g = s + 1 + q;
                tm[s][q] = (g < 4 && (ib + g) < bend)
                    ? Ap[(size_t)(64 * (ib + g) + r) * NW + (ib + s)] : 0ull;
            }
        }

        if (j0 < ib) {
            const ulonglong2* rp = (const ulonglong2*)&colA[j0 - kk][0];
            #pragma unroll
            for (int bp = 0; bp < 32; ++bp) {
                ulonglong2 ww = rp[bp];
                #pragma unroll
                for (int g = 0; g < 4; ++g)
                    acc[g] = orsel2(acc[g], ww.x, ww.y, m0[g], 2 * bp);
            }
        }

        #pragma unroll
        for (int s = 0; s < 4; ++s) {
            const int i = ib + s;
            if (i < bend) {
                part[wv][r] = acc[s];
                __syncthreads();
                if (wv < 2) {
                    u64 red = part[0][r];
                    #pragma unroll
                    for (int p = 1; p < 16; ++p) red |= part[p][r];
                    if (wv == 0) colA[i - kk][r] = red;
                    else Anc[(size_t)(64 * i + r) * NW + kk] = red;
                }
                __syncthreads();
                if (s < 3 && (i + 1) < bend) {
                    const u64* rowp = colA[i - kk];
                    #pragma unroll
                    for (int bi = 0; bi < 4; ++bi) {
                        int b = 4 * wv + bi;
                        u64 w = rowp[b];
                        u32 wl = (u32)w, wh = (u32)(w >> 32);
                        #pragma unroll
                        for (int q = 0; q < 3; ++q) {
                            int g = s + 1 + q;
                            if (g < 4) {
                                u32 sm2 = (u32)(0u - (u32)((tm[s][q] >> b) & 1ull));
                                u32 al = (u32)acc[g] | (wl & sm2);
                                u32 ah = (u32)(acc[g] >> 32) | (wh & sm2);
                                acc[g] = ((u64)ah << 32) | al;
                            }
                        }
                    }
                }
            }
        }
    }
}

// ---------------------------------------------------------------------------
// K6b: boolean matmul  O[r] |= OR_c (P[r] bit c) ? Q[c] : 0, 1024x1024x1024 bits.
// grid (16 row-tiles x 4 c-slices); atomicOr into zero-initialized output.
// ---------------------------------------------------------------------------
__global__ __launch_bounds__(256) void merge_kernel(
    const u64* __restrict__ Pb, int pstr,
    const u64* __restrict__ Qb, int qstr,
    u64* __restrict__ Ob, int ostr)
{
    __shared__ u64 SQ[256][16];   // 32 KB: Q chunk
    __shared__ u64 PL[64][4];     //  2 KB: P words for this c-slice
    const int t  = threadIdx.x;
    const int rb = blockIdx.x;    // 0..15 (64-row tile)
    const int cs = blockIdx.y;    // 0..3  (256-c slice)
    const int r0 = t >> 4;        // 0..15
    const int w  = t & 15;

    // stage Q[256cs .. 256cs+256) words [0,16)
    for (int q = t; q < 256 * 16; q += 256)
        SQ[q >> 4][q & 15] = Qb[(size_t)(256 * cs + (q >> 4)) * qstr + (q & 15)];
    // stage P words [4cs, 4cs+4) for rows [64rb, 64rb+64)
    {
        int rr = t >> 2, b = t & 3;
        PL[rr][b] = Pb[(size_t)(64 * rb + rr) * pstr + 4 * cs + b];
    }
    __syncthreads();

    u64 acc[4] = {0ull, 0ull, 0ull, 0ull};
    #pragma unroll
    for (int hw = 0; hw < 4; ++hw) {
        u64 m0 = PL[r0][hw], m1 = PL[r0 + 16][hw];
        u64 m2 = PL[r0 + 32][hw], m3 = PL[r0 + 48][hw];
        #pragma unroll
        for (int bit = 0; bit < 64; ++bit) {
            u64 qq = SQ[hw * 64 + bit][w];
            acc[0] |= qq & (0ull - ((m0 >> bit) & 1ull));
            acc[1] |= qq & (0ull - ((m1 >> bit) & 1ull));
            acc[2] |= qq & (0ull - ((m2 >> bit) & 1ull));
            acc[3] |= qq & (0ull - ((m3 >> bit) & 1ull));
        }
    }
    #pragma unroll
    for (int g = 0; g < 4; ++g)
        if (acc[g])
            atomicOr(&Ob[(size_t)(64 * rb + r0 + 16 * g) * ostr + w], acc[g]);
}

// ---------------------------------------------------------------------------
// K7: fold valid-edge mask in place: heV[i] = he[i] & allowed(i, .)
// Per-block read-then-write of its OWN 256B row -> no cross-block hazard.
// ---------------------------------------------------------------------------
__global__ __launch_bounds__(256) void fold_kernel(
    const u64* __restrict__ Anc,
    const u16* __restrict__ posr,
    u64* __restrict__ heV)
{
    __shared__ u64 s_anc[NW];
    __shared__ u64 s_he[NW];
    __shared__ u16 s_pr[NN];
    __shared__ int s_fl;
    const int i = blockIdx.x;
    const int t = threadIdx.x;
    const int lane = t & 63;
    const int wave = t >> 6;

    ((int4*)s_pr)[t] = ((const int4*)posr)[t];   // 4 KB posr stage
    if (t == 0) s_fl = posr[i];
    __syncthreads();
    const int pi = s_fl & 0x7FF;
    if (t < NW) {
        s_anc[t] = Anc[(size_t)pi * NW + t];
        s_he[t]  = heV[(size_t)i * NW + t];
    }
    __syncthreads();
    const bool reach_i = (s_fl & 0x4000) != 0;
    for (int c = wave; c < NW; c += 4) {
        int j = (c << 6) + lane;
        int pr = s_pr[j];
        int a = pr & 0x7FF;
        bool b = reach_i
              && (((s_he[c] >> lane) & 1ull) != 0)
              && ((pr & 0x8000) == 0)
              && (((s_anc[a >> 6] >> (a & 63)) & 1ull) == 0);
        u64 m = __ballot(b);
        if (lane == 0) heV[(size_t)i * NW + c] = m;
    }
}

// ---------------------------------------------------------------------------
// K8: expand bits -> f32 dag
// ---------------------------------------------------------------------------
__global__ __launch_bounds__(256) void out_kernel(
    const u64* __restrict__ heV, float* __restrict__ dag)
{
    __shared__ u64 s_v[NW];
    const int i = blockIdx.x;
    const int t = threadIdx.x;
    if (t < NW) s_v[t] = heV[(size_t)i * NW + t];
    __syncthreads();
    int j0 = t * 8;
    u64 v = s_v[j0 >> 6];
    int sh = j0 & 63;
    float4 f0, f1;
    f0.x = ((v >> (sh + 0)) & 1ull) ? 1.f : 0.f;
    f0.y = ((v >> (sh + 1)) & 1ull) ? 1.f : 0.f;
    f0.z = ((v >> (sh + 2)) & 1ull) ? 1.f : 0.f;
    f0.w = ((v >> (sh + 3)) & 1ull) ? 1.f : 0.f;
    f1.x = ((v >> (sh + 4)) & 1ull) ? 1.f : 0.f;
    f1.y = ((v >> (sh + 5)) & 1ull) ? 1.f : 0.f;
    f1.z = ((v >> (sh + 6)) & 1ull) ? 1.f : 0.f;
    f1.w = ((v >> (sh + 7)) & 1ull) ? 1.f : 0.f;
    float4* o = (float4*)(dag + (size_t)i * NN + j0);
    o[0] = f0; o[1] = f1;
}

// ---------------------------------------------------------------------------
extern "C" void kernel_launch(void* const* d_in, const int* in_sizes, int n_in,
                              void* d_out, int out_size, void* d_ws, size_t ws_size,
                              hipStream_t stream) {
    const float* root_logits = (const float*)d_in[0];
    const float* edge_logits = (const float*)d_in[1];
    const float* g_root      = (const float*)d_in[2];
    const float* g_edge      = (const float*)d_in[3];
    float* dag = (float*)d_out;

    // ws (exactly 1 MB, proven in round 1): heBits/heV + Anc
    u64* heV = (u64*)d_ws;                                   // 512 KB
    u64* Anc = (u64*)((char*)d_ws + (512 << 10));            // 512 KB
    // d_out scratch (all dead before fold/out; out writes every dag byte):
    u64* heT    = (u64*)((char*)d_out + (1 << 20));                // 512 KB
    u64* Ap     = (u64*)((char*)d_out + (1 << 20) + (512 << 10));  // 512 KB
    u64* Di     = (u64*)((char*)d_out + (2 << 20));                //  16 KB
    u64* M1     = (u64*)((char*)d_out + (2 << 20) + (64 << 10));   // 128 KB
    u16* posr    = (u16*)((char*)d_out + (2 << 20) + (256 << 10)); //   4 KB
    u16* porderW = (u16*)((char*)d_out + (2 << 20) + (260 << 10)); //   4 KB
    int* nrPtr   = (int*)((char*)d_out + (2 << 20) + (264 << 10)); //   4 B

    prep_kernel     <<<NN, 256, 0, stream>>>(edge_logits, g_edge, heV);
    order_kernel    <<<1, 1024, 0, stream>>>(root_logits, g_root, heV,
                                             posr, porderW, nrPtr);
    transpose_kernel<<<NN / 2, 64, 0, stream>>>(heV, heT);
    apbuild_kernel  <<<NN, 256, 0, stream>>>(heT, porderW, nrPtr, Ap);
    diag_kernel     <<<NW, 64, 0, stream>>>(Ap, Di, M1, Anc);
    ap2_kernel      <<<dim3(NW, NW), 64, 0, stream>>>(Di, Ap);
    colhalf_kernel  <<<NW, 1024, 0, stream>>>(Ap, Di, Anc);
    // M1 = Ap'_cross (B rows, T word-cols) * A*
    merge_kernel<<<dim3(16, 4), 256, 0, stream>>>(Ap + (size_t)1024 * NW, NW,
                                                  Anc, NW, M1, 16);
    // Anc[B,T] = B* * M1   (B* = words 16.. of B rows)
    merge_kernel<<<dim3(16, 4), 256, 0, stream>>>(Anc + (size_t)1024 * NW + 16, NW,
                                                  M1, 16,
                                                  Anc + (size_t)1024 * NW, NW);
    fold_kernel     <<<NN, 256, 0, stream>>>(Anc, posr, heV);
    out_kernel      <<<NN, 256, 0, stream>>>(heV, dag);
}

// Round 7
// 171.140 us; speedup vs baseline: 1.1142x; 1.1142x over previous
//
#include <hip/hip_runtime.h>
#include <stdint.h>

typedef unsigned long long u64;
typedef unsigned int u32;
typedef unsigned short u16;

#define NN 2048
#define NW 32    // u64 words per 2048-bit row

#if __has_builtin(__builtin_amdgcn_sbfe)
#define SBFE(x, o) ((u32)__builtin_amdgcn_sbfe((int)(x), (u32)(o), 1u))
#else
#define SBFE(x, o) ((u32)(-(int)(((x) >> (o)) & 1u)))
#endif

static __device__ __forceinline__ bool gumbel_gt(float x, float g0, float g1) {
    // jax.nn.log_sigmoid(x) = -(max(-x,0) + log1p(exp(-|x|)))
    float L = log1pf(expf(-fabsf(x)));
    float a = (-(fmaxf(-x, 0.f) + L)) + g0;   // ye[0]
    float b = (-(fmaxf( x, 0.f) + L)) + g1;   // ye[1]
    return a > b;
}

// acc |= (bit b0 of m ? w0 : 0) | (bit b0+1 of m ? w1 : 0); b0 even, compile-time
static __device__ __forceinline__ u64 orsel2(u64 acc, u64 w0, u64 w1, u64 m, int b0) {
    u32 mm = (b0 < 32) ? (u32)m : (u32)(m >> 32);
    int sh = b0 & 31;
    u32 s0 = SBFE(mm, sh);
    u32 s1 = SBFE(mm, sh + 1);
    u32 al = (u32)acc | ((u32)w0 & s0) | ((u32)w1 & s1);
    u32 ah = (u32)(acc >> 32) | ((u32)(w0 >> 32) & s0) | ((u32)(w1 >> 32) & s1);
    return ((u64)ah << 32) | al;
}

// ---------------------------------------------------------------------------
// K1: hard-edge bitmask  he[i][j]
// ---------------------------------------------------------------------------
__global__ __launch_bounds__(256) void prep_kernel(
    const float* __restrict__ edge_logits,
    const float* __restrict__ g_edge,
    u64* __restrict__ heBits)
{
    const int i = blockIdx.x;
    const int t = threadIdx.x;
    const int lane = t & 63;
    const int wave = t >> 6;
    for (int c = wave; c < NW; c += 4) {
        int j = (c << 6) + lane;
        float x  = edge_logits[(size_t)i * NN + j];
        float g0 = g_edge[(size_t)i * (2 * NN) + j];
        float g1 = g_edge[(size_t)i * (2 * NN) + NN + j];
        u64 m = __ballot(gumbel_gt(x, g0, g1));
        if (lane == 0) heBits[(size_t)i * NW + c] = m;
    }
}

// ---------------------------------------------------------------------------
// K2: level-synchronous BFS order (unchanged — proven).
// ---------------------------------------------------------------------------
__global__ __launch_bounds__(1024) void order_kernel(
    const float* __restrict__ root_logits,
    const float* __restrict__ g_root,
    const u64* __restrict__ heBits,
    u16* __restrict__ posr,
    u16* __restrict__ porderW,
    int* __restrict__ nrPtr)
{
    __shared__ u64 s_root[NW], s_enq[NW], s_F[NW];
    __shared__ u64 s_U[16][NW];
    __shared__ u64 s_Pg[16][NW];
    __shared__ int s_porder[NN];
    __shared__ u16 s_pos[NN];
    __shared__ u16 s_f[NN];
    __shared__ u16 s_rk[NN];
    __shared__ int s_cnt[NN];
    __shared__ int s_wsum[16], s_woff[16];
    __shared__ int s_base, s_lo, s_levcnt, s_newcnt, s_nr;

    const int t    = threadIdx.x;
    const int lane = t & 63;
    const int wid  = t >> 6;
    const int half = lane >> 5;
    const int w    = lane & 31;

    for (int p = 0; p < 2; ++p) {
        int j = p * 1024 + t;
        bool rb = gumbel_gt(root_logits[j], g_root[j], g_root[NN + j]);
        u64 m = __ballot(rb);
        if (lane == 0) s_root[j >> 6] = m;
    }
    __syncthreads();
    for (int p = 0; p < 2; ++p) {
        int j = p * 1024 + t;
        int ww = j >> 6; u64 bit = 1ull << (j & 63);
        if (s_root[ww] & bit) {
            int r = 0;
            for (int k = 0; k < ww; ++k) r += __popcll(s_root[k]);
            r += __popcll(s_root[ww] & (bit - 1ull));
            s_pos[j] = (u16)r;
            s_porder[r] = j;
        }
    }
    if (t < NW) s_enq[t] = s_root[t];
    if (t == 0) {
        int tl = 0;
        for (int k = 0; k < NW; ++k) tl += __popcll(s_root[k]);
        s_lo = 0; s_levcnt = tl; s_base = tl; s_nr = tl;
    }
    __syncthreads();

    while (s_levcnt > 0 && s_base < NN) {
        const int lo = s_lo, cnt = s_levcnt, base = s_base;
        const int seglen = (cnt + 15) >> 4;
        const int s0 = wid * seglen;
        const int s1 = (s0 + seglen < cnt) ? (s0 + seglen) : cnt;

        {
            u64 acc = 0;
            for (int m = s0 + half; m < s1; m += 2)
                acc |= heBits[(size_t)s_porder[lo + m] * NW + w];
            acc |= __shfl(acc, lane ^ 32);
            if (half == 0) s_U[wid][w] = acc;
        }
        __syncthreads();
        if (t < NW) {
            u64 o = 0;
            #pragma unroll
            for (int s = 0; s < 16; ++s) o |= s_U[s][t];
            s_F[t] = o & ~s_enq[t] & ~s_root[t];
        }
        __syncthreads();
        if (t < 512) {
            int s = t >> 5, ww = t & 31;
            u64 p = 0;
            for (int s2 = 0; s2 < s; ++s2) p |= s_U[s2][ww];
            s_Pg[s][ww] = p & s_F[ww];
        }
        __syncthreads();
        {
            u64 P  = s_Pg[wid][w];
            u64 Fw = s_F[w];
            int myidx = (s0 + lane < s1) ? s_porder[lo + s0 + lane] : 0;
            for (int m = s0; m < s1; m += 2) {
                int m0 = m + half;
                int rowi = __shfl(myidx, (m - s0) + half);
                u64 r = 0;
                if (m0 < s1) r = heBits[(size_t)rowi * NW + w];
                u64 v = r & Fw & ~P;
                u64 vlo = __shfl(v, w);
                u64 B = half ? (v & ~vlo) : v;
                int pc = __popcll(B);
                int inc = pc;
                #pragma unroll
                for (int d = 1; d < 32; d <<= 1) {
                    int u2 = __shfl_up(inc, d, 64);
                    if (w >= d) inc += u2;
                }
                int excl = inc - pc;
                int tot = __shfl(inc, (half << 5) | 31);
                if (w == 0 && m0 < s1) s_cnt[m0] = tot;
                u64 mm = B;
                int idx = excl;
                while (mm) {
                    int b = __ffsll(mm) - 1; mm &= mm - 1;
                    int j = (w << 6) + b;
                    s_f[j]  = (u16)m0;
                    s_rk[j] = (u16)idx++;
                }
                P |= B | __shfl(B, lane ^ 32);
            }
        }
        __syncthreads();
        {
            int b0 = 2 * t, b1 = 2 * t + 1;
            int c0 = (b0 < cnt) ? s_cnt[b0] : 0;
            int c1 = (b1 < cnt) ? s_cnt[b1] : 0;
            int pairv = c0 + c1;
            int incl = pairv;
            for (int d = 1; d < 64; d <<= 1) {
                int v = __shfl_up(incl, d, 64);
                if (lane >= d) incl += v;
            }
            if (lane == 63) s_wsum[wid] = incl;
            __syncthreads();
            if (t < 16) {
                int v = s_wsum[t];
                int inc2 = v;
                for (int d = 1; d < 16; d <<= 1) {
                    int u = __shfl_up(inc2, d, 16);
                    if (t >= d) inc2 += u;
                }
                s_woff[t] = inc2 - v;
                if (t == 15) s_newcnt = inc2;
            }
            __syncthreads();
            int excl = s_woff[wid] + (incl - pairv);
            if (b0 < cnt) s_cnt[b0] = excl;
            if (b1 < cnt) s_cnt[b1] = excl + c0;
        }
        __syncthreads();
        for (int p = 0; p < 2; ++p) {
            int j = p * 1024 + t;
            int ww = j >> 6;
            if ((s_F[ww] >> (j & 63)) & 1ull) {
                int slot = base + s_cnt[s_f[j]] + s_rk[j];
                s_pos[j] = (u16)slot;
                s_porder[slot] = j;
            }
        }
        if (t < NW) s_enq[t] |= s_F[t];
        __syncthreads();
        if (t == 0) { s_lo = base; s_levcnt = s_newcnt; s_base = base + s_newcnt; }
        __syncthreads();
    }

    for (int p = 0; p < 2; ++p) {
        int j = p * 1024 + t;
        int ww = j >> 6; u64 bit = 1ull << (j & 63);
        if (!((s_enq[ww] >> (j & 63)) & 1ull)) {
            int rk = 0;
            for (int k2 = 0; k2 < ww; ++k2) rk += __popcll(~s_enq[k2]);
            rk += __popcll(~s_enq[ww] & (bit - 1ull));
            int slot = s_base + rk;
            s_pos[j] = (u16)slot;
            s_porder[slot] = j;
        }
    }
    __syncthreads();
    for (int p = 0; p < 2; ++p) {
        int j = p * 1024 + t;
        int fl = s_pos[j];
        if ((s_root[j >> 6] >> (j & 63)) & 1ull) fl |= 0x8000;
        if ((s_enq[j >> 6]  >> (j & 63)) & 1ull) fl |= 0x4000;
        posr[j] = (u16)fl;
        porderW[j] = (u16)s_porder[j];
    }
    if (t == 0) *nrPtr = s_nr;
}

// ---------------------------------------------------------------------------
// K3: bit-transpose heBits -> heT
// ---------------------------------------------------------------------------
__global__ __launch_bounds__(64) void transpose_kernel(
    const u64* __restrict__ heBits, u64* __restrict__ heT)
{
    const int ti = blockIdx.x >> 5;
    const int tj = blockIdx.x & 31;
    const int r = threadIdx.x;
    u64 w = heBits[(size_t)(64 * ti + r) * NW + tj];
    u64 out = 0;
    #pragma unroll
    for (int b = 0; b < 64; ++b) {
        u64 m = __ballot(((w >> b) & 1ull) != 0);
        if (b == r) out = m;
    }
    heT[(size_t)(64 * tj + r) * NW + ti] = out;
}

// ---------------------------------------------------------------------------
// K4: permuted strict-lower parent matrix
// ---------------------------------------------------------------------------
__global__ __launch_bounds__(256) void apbuild_kernel(
    const u64* __restrict__ heT, const u16* __restrict__ porderW,
    const int* __restrict__ nrPtr, u64* __restrict__ Ap)
{
    __shared__ u64 s_row[NW];
    __shared__ u16 s_inv[NN];
    __shared__ int s_invb, s_nr;
    const int b = blockIdx.x;
    const int t = threadIdx.x;
    for (int q = t; q < NN; q += 256) s_inv[q] = porderW[q];
    if (t == 0) { s_invb = porderW[b]; s_nr = *nrPtr; }
    __syncthreads();
    if (t < NW) s_row[t] = heT[(size_t)s_invb * NW + t];
    __syncthreads();
    const bool bge = (b >= s_nr);
    for (int pass = 0; pass < 8; ++pass) {
        int a = pass * 256 + t;
        int ia = s_inv[a];
        bool bit = bge && (a < b) &&
                   (((s_row[ia >> 6] >> (ia & 63)) & 1ull) != 0);
        u64 m = __ballot(bit);
        if ((t & 63) == 0) Ap[(size_t)b * NW + (a >> 6)] = m;
    }
}

// ---------------------------------------------------------------------------
// K5: diagonal closures  Di[k] = closure(Ap_kk) (reflexive), 6 squarings
// ---------------------------------------------------------------------------
__global__ __launch_bounds__(64) void diag_kernel(
    const u64* __restrict__ Ap, u64* __restrict__ Di)
{
    __shared__ u64 sm[64];
    const int r = threadIdx.x;
    const int k = blockIdx.x;
    u64 M = Ap[(size_t)(64 * k + r) * NW + k] | (1ull << r);
    for (int s = 0; s < 6; ++s) {
        sm[r] = M;
        __syncthreads();
        u64 acc = 0;
        #pragma unroll
        for (int b = 0; b < 64; ++b)
            acc |= sm[b] & (0ull - ((M >> b) & 1ull));
        __syncthreads();
        M = acc;
    }
    Di[64 * k + r] = M;
}

// ---------------------------------------------------------------------------
// K5b: premultiply Ap_ij := Di * Ap_ij for all j < i (incl. cross blocks)
// ---------------------------------------------------------------------------
__global__ __launch_bounds__(64) void ap2_kernel(
    const u64* __restrict__ Di, u64* __restrict__ Ap)
{
    const int i = blockIdx.x;
    const int j = blockIdx.y;
    if (j >= i) return;
    __shared__ u64 sm[64];
    const int r = threadIdx.x;
    u64 d = Di[64 * i + r];
    sm[r] = Ap[(size_t)(64 * i + r) * NW + j];
    __syncthreads();
    u64 acc = 0;
    #pragma unroll
    for (int b = 0; b < 64; ++b)
        acc |= sm[b] & (0ull - ((d >> b) & 1ull));
    Ap[(size_t)(64 * i + r) * NW + j] = acc;
}

// ---------------------------------------------------------------------------
// K6: half-triangle forward-substitution closure (unchanged — proven).
// ---------------------------------------------------------------------------
__global__ __launch_bounds__(1024) void colhalf_kernel(
    const u64* __restrict__ Ap, const u64* __restrict__ Di,
    u64* __restrict__ Anc)
{
    __shared__ __align__(16) u64 colA[16][64];
    __shared__ u64 part[16][64];
    const int t  = threadIdx.x;
    const int r  = t & 63;
    const int wv = t >> 6;
    const int k    = blockIdx.x & 15;
    const int hb   = blockIdx.x >> 4;
    const int base = hb << 4;
    const int bend = base + 16;
    const int kk   = base + k;

    for (int row = t; row < 64 * kk; row += 1024)
        Anc[(size_t)row * NW + kk] = 0ull;

    if (t < 64) {
        u64 d = Di[64 * kk + r];
        colA[0][r] = d;
        Anc[(size_t)(64 * kk + r) * NW + kk] = d;
    }
    __syncthreads();

    const int j0 = kk + wv;

    for (int ib = kk + 1; ib < bend; ib += 4) {
        u64 m0[4], acc[4];
        #pragma unroll
        for (int g = 0; g < 4; ++g) {
            int ig = ib + g;
            bool v = (ig < bend);
            m0[g] = (v && (j0 < ib)) ? Ap[(size_t)(64 * ig + r) * NW + j0] : 0ull;
            acc[g] = 0ull;
        }
        u64 tm[3][3];
        #pragma unroll
        for (int s = 0; s < 3; ++s) {
            #pragma unroll
            for (int q = 0; q < 3; ++q) {
                int g = s + 1 + q;
                tm[s][q] = (g < 4 && (ib + g) < bend)
                    ? Ap[(size_t)(64 * (ib + g) + r) * NW + (ib + s)] : 0ull;
            }
        }

        if (j0 < ib) {
            const ulonglong2* rp = (const ulonglong2*)&colA[j0 - kk][0];
            #pragma unroll
            for (int bp = 0; bp < 32; ++bp) {
                ulonglong2 ww = rp[bp];
                #pragma unroll
                for (int g = 0; g < 4; ++g)
                    acc[g] = orsel2(acc[g], ww.x, ww.y, m0[g], 2 * bp);
            }
        }

        #pragma unroll
        for (int s = 0; s < 4; ++s) {
            const int i = ib + s;
            if (i < bend) {
                part[wv][r] = acc[s];
                __syncthreads();
                if (wv < 2) {
                    u64 red = part[0][r];
                    #pragma unroll
                    for (int p = 1; p < 16; ++p) red |= part[p][r];
                    if (wv == 0) colA[i - kk][r] = red;
                    else Anc[(size_t)(64 * i + r) * NW + kk] = red;
                }
                __syncthreads();
                if (s < 3 && (i + 1) < bend) {
                    const u64* rowp = colA[i - kk];
                    #pragma unroll
                    for (int bi = 0; bi < 4; ++bi) {
                        int b = 4 * wv + bi;
                        u64 w = rowp[b];
                        u32 wl = (u32)w, wh = (u32)(w >> 32);
                        #pragma unroll
                        for (int q = 0; q < 3; ++q) {
                            int g = s + 1 + q;
                            if (g < 4) {
                                u32 sm2 = (u32)(0u - (u32)((tm[s][q] >> b) & 1ull));
                                u32 al = (u32)acc[g] | (wl & sm2);
                                u32 ah = (u32)(acc[g] >> 32) | (wh & sm2);
                                acc[g] = ((u64)ah << 32) | al;
                            }
                        }
                    }
                }
            }
        }
    }
}

// ---------------------------------------------------------------------------
// K6b: boolean matmul O[r][w] = OR_c (P[r] bit c) ? Q[c][w] : 0 ; 1024x1024x1024.
// v2: no atomics — each output word owned by one thread (full c-reduction).
// grid 64 blocks x 256 thr. Lane = (grp = lane>>4, w = lane&15); lane reads
// c = grp (mod 4) slices -> 64 distinct LDS addrs/inst, partials combined by
// 2 shfl_xor. Wave wv owns rows 4wv..4wv+3 (4 accs/thread).
// ---------------------------------------------------------------------------
__global__ __launch_bounds__(256) void merge_kernel(
    const u64* __restrict__ Pb, int pstr,
    const u64* __restrict__ Qb, int qstr,
    u64* __restrict__ Ob, int ostr)
{
    __shared__ u64 SQ[256][17];   // 34 KB, pad 17 -> uniform (c+w) bank spread
    __shared__ u64 PL[16][16];    //  2 KB
    const int t    = threadIdx.x;
    const int lane = t & 63;
    const int wv   = t >> 6;      // 0..3
    const int grp  = (lane >> 4); // 0..3
    const int w    = lane & 15;
    const int rb   = blockIdx.x;  // 16-row tile

    PL[t >> 4][t & 15] = Pb[(size_t)(16 * rb + (t >> 4)) * pstr + (t & 15)];

    u64 acc0 = 0, acc1 = 0, acc2 = 0, acc3 = 0;

    for (int cs = 0; cs < 4; ++cs) {
        __syncthreads();
        for (int q = t; q < 4096; q += 256)
            SQ[q >> 4][q & 15] = Qb[(size_t)(256 * cs + (q >> 4)) * qstr + (q & 15)];
        __syncthreads();
        #pragma unroll
        for (int cw = 0; cw < 4; ++cw) {
            u64 m0 = PL[4 * wv + 0][cs * 4 + cw];
            u64 m1 = PL[4 * wv + 1][cs * 4 + cw];
            u64 m2 = PL[4 * wv + 2][cs * 4 + cw];
            u64 m3 = PL[4 * wv + 3][cs * 4 + cw];
            #pragma unroll
            for (int cc = 0; cc < 16; ++cc) {
                u64 qq = SQ[cw * 64 + cc * 4 + grp][w];
                int sh = (cc & 7) * 4 + grp;
                u32 h0 = (cc < 8) ? (u32)m0 : (u32)(m0 >> 32);
                u32 h1 = (cc < 8) ? (u32)m1 : (u32)(m1 >> 32);
                u32 h2 = (cc < 8) ? (u32)m2 : (u32)(m2 >> 32);
                u32 h3 = (cc < 8) ? (u32)m3 : (u32)(m3 >> 32);
                u32 ql = (u32)qq, qh = (u32)(qq >> 32);
                u32 s;
                s = SBFE(h0, sh);
                acc0 = ((u64)(((u32)(acc0 >> 32)) | (qh & s)) << 32) | (((u32)acc0) | (ql & s));
                s = SBFE(h1, sh);
                acc1 = ((u64)(((u32)(acc1 >> 32)) | (qh & s)) << 32) | (((u32)acc1) | (ql & s));
                s = SBFE(h2, sh);
                acc2 = ((u64)(((u32)(acc2 >> 32)) | (qh & s)) << 32) | (((u32)acc2) | (ql & s));
                s = SBFE(h3, sh);
                acc3 = ((u64)(((u32)(acc3 >> 32)) | (qh & s)) << 32) | (((u32)acc3) | (ql & s));
            }
        }
    }

    // combine the 4 c-phase partials (lanes w, w+16, w+32, w+48)
    acc0 |= __shfl_xor(acc0, 16); acc0 |= __shfl_xor(acc0, 32);
    acc1 |= __shfl_xor(acc1, 16); acc1 |= __shfl_xor(acc1, 32);
    acc2 |= __shfl_xor(acc2, 16); acc2 |= __shfl_xor(acc2, 32);
    acc3 |= __shfl_xor(acc3, 16); acc3 |= __shfl_xor(acc3, 32);

    if (grp == 0) {
        size_t base = (size_t)(16 * rb + 4 * wv) * ostr + w;
        Ob[base] = acc0;
        Ob[base + ostr] = acc1;
        Ob[base + 2 * (size_t)ostr] = acc2;
        Ob[base + 3 * (size_t)ostr] = acc3;
    }
}

// ---------------------------------------------------------------------------
// K7: fold valid-edge mask in place: heV[i] = he[i] & allowed(i, .)
// ---------------------------------------------------------------------------
__global__ __launch_bounds__(256) void fold_kernel(
    const u64* __restrict__ Anc,
    const u16* __restrict__ posr,
    u64* __restrict__ heV)
{
    __shared__ u64 s_anc[NW];
    __shared__ u64 s_he[NW];
    __shared__ u16 s_pr[NN];
    __shared__ int s_fl;
    const int i = blockIdx.x;
    const int t = threadIdx.x;
    const int lane = t & 63;
    const int wave = t >> 6;

    ((int4*)s_pr)[t] = ((const int4*)posr)[t];
    if (t == 0) s_fl = posr[i];
    __syncthreads();
    const int pi = s_fl & 0x7FF;
    if (t < NW) {
        s_anc[t] = Anc[(size_t)pi * NW + t];
        s_he[t]  = heV[(size_t)i * NW + t];
    }
    __syncthreads();
    const bool reach_i = (s_fl & 0x4000) != 0;
    for (int c = wave; c < NW; c += 4) {
        int j = (c << 6) + lane;
        int pr = s_pr[j];
        int a = pr & 0x7FF;
        bool b = reach_i
              && (((s_he[c] >> lane) & 1ull) != 0)
              && ((pr & 0x8000) == 0)
              && (((s_anc[a >> 6] >> (a & 63)) & 1ull) == 0);
        u64 m = __ballot(b);
        if (lane == 0) heV[(size_t)i * NW + c] = m;
    }
}

// ---------------------------------------------------------------------------
// K8: expand bits -> f32 dag
// ---------------------------------------------------------------------------
__global__ __launch_bounds__(256) void out_kernel(
    const u64* __restrict__ heV, float* __restrict__ dag)
{
    __shared__ u64 s_v[NW];
    const int i = blockIdx.x;
    const int t = threadIdx.x;
    if (t < NW) s_v[t] = heV[(size_t)i * NW + t];
    __syncthreads();
    int j0 = t * 8;
    u64 v = s_v[j0 >> 6];
    int sh = j0 & 63;
    float4 f0, f1;
    f0.x = ((v >> (sh + 0)) & 1ull) ? 1.f : 0.f;
    f0.y = ((v >> (sh + 1)) & 1ull) ? 1.f : 0.f;
    f0.z = ((v >> (sh + 2)) & 1ull) ? 1.f : 0.f;
    f0.w = ((v >> (sh + 3)) & 1ull) ? 1.f : 0.f;
    f1.x = ((v >> (sh + 4)) & 1ull) ? 1.f : 0.f;
    f1.y = ((v >> (sh + 5)) & 1ull) ? 1.f : 0.f;
    f1.z = ((v >> (sh + 6)) & 1ull) ? 1.f : 0.f;
    f1.w = ((v >> (sh + 7)) & 1ull) ? 1.f : 0.f;
    float4* o = (float4*)(dag + (size_t)i * NN + j0);
    o[0] = f0; o[1] = f1;
}

// ---------------------------------------------------------------------------
extern "C" void kernel_launch(void* const* d_in, const int* in_sizes, int n_in,
                              void* d_out, int out_size, void* d_ws, size_t ws_size,
                              hipStream_t stream) {
    const float* root_logits = (const float*)d_in[0];
    const float* edge_logits = (const float*)d_in[1];
    const float* g_root      = (const float*)d_in[2];
    const float* g_edge      = (const float*)d_in[3];
    float* dag = (float*)d_out;

    // ws (1 MB, proven): heV + Anc
    u64* heV = (u64*)d_ws;                                   // 512 KB
    u64* Anc = (u64*)((char*)d_ws + (512 << 10));            // 512 KB
    // d_out scratch (dead before fold/out; out writes every dag byte):
    u64* heT    = (u64*)((char*)d_out + (1 << 20));                // 512 KB
    u64* Ap     = (u64*)((char*)d_out + (1 << 20) + (512 << 10));  // 512 KB
    u64* Di     = (u64*)((char*)d_out + (2 << 20));                //  16 KB
    u64* M1     = (u64*)((char*)d_out + (2 << 20) + (64 << 10));   // 128 KB
    u16* posr    = (u16*)((char*)d_out + (2 << 20) + (256 << 10)); //   4 KB
    u16* porderW = (u16*)((char*)d_out + (2 << 20) + (260 << 10)); //   4 KB
    int* nrPtr   = (int*)((char*)d_out + (2 << 20) + (264 << 10)); //   4 B

    prep_kernel     <<<NN, 256, 0, stream>>>(edge_logits, g_edge, heV);
    order_kernel    <<<1, 1024, 0, stream>>>(root_logits, g_root, heV,
                                             posr, porderW, nrPtr);
    transpose_kernel<<<NN / 2, 64, 0, stream>>>(heV, heT);
    apbuild_kernel  <<<NN, 256, 0, stream>>>(heT, porderW, nrPtr, Ap);
    diag_kernel     <<<NW, 64, 0, stream>>>(Ap, Di);
    ap2_kernel      <<<dim3(NW, NW), 64, 0, stream>>>(Di, Ap);
    colhalf_kernel  <<<NW, 1024, 0, stream>>>(Ap, Di, Anc);
    // M1 = C' * A*   (C' rows = Ap B-rows words 0..15; A* = Anc T-rows)
    merge_kernel<<<64, 256, 0, stream>>>(Ap + (size_t)1024 * NW, NW,
                                         Anc, NW, M1, 16);
    // Anc[B, T-words] = B* * M1   (B* = Anc B-rows words 16..31)
    merge_kernel<<<64, 256, 0, stream>>>(Anc + (size_t)1024 * NW + 16, NW,
                                         M1, 16,
                                         Anc + (size_t)1024 * NW, NW);
    fold_kernel     <<<NN, 256, 0, stream>>>(Anc, posr, heV);
    out_kernel      <<<NN, 256, 0, stream>>>(heV, dag);
}

// Round 8
// 165.974 us; speedup vs baseline: 1.1489x; 1.0311x over previous
//
#include <hip/hip_runtime.h>
#include <stdint.h>

typedef unsigned long long u64;
typedef unsigned int u32;
typedef unsigned short u16;

#define NN 2048
#define NW 32    // u64 words per 2048-bit row

#if __has_builtin(__builtin_amdgcn_sbfe)
#define SBFE(x, o) ((u32)__builtin_amdgcn_sbfe((int)(x), (u32)(o), 1u))
#else
#define SBFE(x, o) ((u32)(-(int)(((x) >> (o)) & 1u)))
#endif

static __device__ __forceinline__ bool gumbel_gt(float x, float g0, float g1) {
    // jax.nn.log_sigmoid(x) = -(max(-x,0) + log1p(exp(-|x|)))
    float L = log1pf(expf(-fabsf(x)));
    float a = (-(fmaxf(-x, 0.f) + L)) + g0;   // ye[0]
    float b = (-(fmaxf( x, 0.f) + L)) + g1;   // ye[1]
    return a > b;
}

// acc |= (bit b0 of m ? w0 : 0) | (bit b0+1 of m ? w1 : 0); b0 even, compile-time
static __device__ __forceinline__ u64 orsel2(u64 acc, u64 w0, u64 w1, u64 m, int b0) {
    u32 mm = (b0 < 32) ? (u32)m : (u32)(m >> 32);
    int sh = b0 & 31;
    u32 s0 = SBFE(mm, sh);
    u32 s1 = SBFE(mm, sh + 1);
    u32 al = (u32)acc | ((u32)w0 & s0) | ((u32)w1 & s1);
    u32 ah = (u32)(acc >> 32) | ((u32)(w0 >> 32) & s0) | ((u32)(w1 >> 32) & s1);
    return ((u64)ah << 32) | al;
}

// ---------------------------------------------------------------------------
// K1: hard-edge bitmask  he[i][j]
// ---------------------------------------------------------------------------
__global__ __launch_bounds__(256) void prep_kernel(
    const float* __restrict__ edge_logits,
    const float* __restrict__ g_edge,
    u64* __restrict__ heBits)
{
    const int i = blockIdx.x;
    const int t = threadIdx.x;
    const int lane = t & 63;
    const int wave = t >> 6;
    for (int c = wave; c < NW; c += 4) {
        int j = (c << 6) + lane;
        float x  = edge_logits[(size_t)i * NN + j];
        float g0 = g_edge[(size_t)i * (2 * NN) + j];
        float g1 = g_edge[(size_t)i * (2 * NN) + NN + j];
        u64 m = __ballot(gumbel_gt(x, g0, g1));
        if (lane == 0) heBits[(size_t)i * NW + c] = m;
    }
}

// ---------------------------------------------------------------------------
// K2: level-synchronous BFS order (round-4 proven core + phase-C prefetch).
// ---------------------------------------------------------------------------
__global__ __launch_bounds__(1024) void order_kernel(
    const float* __restrict__ root_logits,
    const float* __restrict__ g_root,
    const u64* __restrict__ heBits,
    u16* __restrict__ posr,
    u16* __restrict__ porderW,
    int* __restrict__ nrPtr)
{
    __shared__ u64 s_root[NW], s_enq[NW], s_F[NW];
    __shared__ u64 s_U[16][NW];
    __shared__ u64 s_Pg[16][NW];
    __shared__ int s_porder[NN];
    __shared__ u16 s_pos[NN];
    __shared__ u16 s_f[NN];
    __shared__ u16 s_rk[NN];
    __shared__ int s_cnt[NN];
    __shared__ int s_wsum[16], s_woff[16];
    __shared__ int s_base, s_lo, s_levcnt, s_newcnt, s_nr;

    const int t    = threadIdx.x;
    const int lane = t & 63;
    const int wid  = t >> 6;
    const int half = lane >> 5;
    const int w    = lane & 31;

    for (int p = 0; p < 2; ++p) {
        int j = p * 1024 + t;
        bool rb = gumbel_gt(root_logits[j], g_root[j], g_root[NN + j]);
        u64 m = __ballot(rb);
        if (lane == 0) s_root[j >> 6] = m;
    }
    __syncthreads();
    for (int p = 0; p < 2; ++p) {
        int j = p * 1024 + t;
        int ww = j >> 6; u64 bit = 1ull << (j & 63);
        if (s_root[ww] & bit) {
            int r = 0;
            for (int k = 0; k < ww; ++k) r += __popcll(s_root[k]);
            r += __popcll(s_root[ww] & (bit - 1ull));
            s_pos[j] = (u16)r;
            s_porder[r] = j;
        }
    }
    if (t < NW) s_enq[t] = s_root[t];
    if (t == 0) {
        int tl = 0;
        for (int k = 0; k < NW; ++k) tl += __popcll(s_root[k]);
        s_lo = 0; s_levcnt = tl; s_base = tl; s_nr = tl;
    }
    __syncthreads();

    while (s_levcnt > 0 && s_base < NN) {
        const int lo = s_lo, cnt = s_levcnt, base = s_base;
        const int seglen = (cnt + 15) >> 4;
        const int s0 = wid * seglen;
        const int s1 = (s0 + seglen < cnt) ? (s0 + seglen) : cnt;

        {
            u64 acc = 0;
            for (int m = s0 + half; m < s1; m += 2)
                acc |= heBits[(size_t)s_porder[lo + m] * NW + w];
            acc |= __shfl(acc, lane ^ 32);
            if (half == 0) s_U[wid][w] = acc;
        }
        __syncthreads();
        if (t < NW) {
            u64 o = 0;
            #pragma unroll
            for (int s = 0; s < 16; ++s) o |= s_U[s][t];
            s_F[t] = o & ~s_enq[t] & ~s_root[t];
        }
        __syncthreads();
        if (t < 512) {
            int s = t >> 5, ww = t & 31;
            u64 p = 0;
            for (int s2 = 0; s2 < s; ++s2) p |= s_U[s2][ww];
            s_Pg[s][ww] = p & s_F[ww];
        }
        __syncthreads();
        {
            u64 P  = s_Pg[wid][w];
            u64 Fw = s_F[w];
            int myidx = (s0 + lane < s1) ? s_porder[lo + s0 + lane] : 0;
            // prefetch first row
            u64 rnext = 0;
            {
                int rowi0 = __shfl(myidx, half);
                if (s0 + half < s1) rnext = heBits[(size_t)rowi0 * NW + w];
            }
            for (int m = s0; m < s1; m += 2) {
                int m0 = m + half;
                u64 r = rnext;
                {   // prefetch next pair's row (overlaps the ALU chain below)
                    int sidx = (m + 2 - s0) + half;
                    if (sidx > 63) sidx = 0;
                    int rowin = __shfl(myidx, sidx);
                    rnext = 0;
                    if (m + 2 + half < s1) rnext = heBits[(size_t)rowin * NW + w];
                }
                u64 v = (m0 < s1) ? (r & Fw & ~P) : 0ull;
                u64 vlo = __shfl(v, w);
                u64 B = half ? (v & ~vlo) : v;
                int pc = __popcll(B);
                int inc = pc;
                #pragma unroll
                for (int d = 1; d < 32; d <<= 1) {
                    int u2 = __shfl_up(inc, d, 64);
                    if (w >= d) inc += u2;
                }
                int excl = inc - pc;
                int tot = __shfl(inc, (half << 5) | 31);
                if (w == 0 && m0 < s1) s_cnt[m0] = tot;
                u64 mm = B;
                int idx = excl;
                while (mm) {
                    int b = __ffsll(mm) - 1; mm &= mm - 1;
                    int j = (w << 6) + b;
                    s_f[j]  = (u16)m0;
                    s_rk[j] = (u16)idx++;
                }
                P |= B | __shfl(B, lane ^ 32);
            }
        }
        __syncthreads();
        {
            int b0 = 2 * t, b1 = 2 * t + 1;
            int c0 = (b0 < cnt) ? s_cnt[b0] : 0;
            int c1 = (b1 < cnt) ? s_cnt[b1] : 0;
            int pairv = c0 + c1;
            int incl = pairv;
            for (int d = 1; d < 64; d <<= 1) {
                int v = __shfl_up(incl, d, 64);
                if (lane >= d) incl += v;
            }
            if (lane == 63) s_wsum[wid] = incl;
            __syncthreads();
            if (t < 16) {
                int v = s_wsum[t];
                int inc2 = v;
                for (int d = 1; d < 16; d <<= 1) {
                    int u = __shfl_up(inc2, d, 16);
                    if (t >= d) inc2 += u;
                }
                s_woff[t] = inc2 - v;
                if (t == 15) s_newcnt = inc2;
            }
            __syncthreads();
            int excl = s_woff[wid] + (incl - pairv);
            if (b0 < cnt) s_cnt[b0] = excl;
            if (b1 < cnt) s_cnt[b1] = excl + c0;
        }
        __syncthreads();
        for (int p = 0; p < 2; ++p) {
            int j = p * 1024 + t;
            int ww = j >> 6;
            if ((s_F[ww] >> (j & 63)) & 1ull) {
                int slot = base + s_cnt[s_f[j]] + s_rk[j];
                s_pos[j] = (u16)slot;
                s_porder[slot] = j;
            }
        }
        if (t < NW) s_enq[t] |= s_F[t];
        __syncthreads();
        if (t == 0) { s_lo = base; s_levcnt = s_newcnt; s_base = base + s_newcnt; }
        __syncthreads();
    }

    for (int p = 0; p < 2; ++p) {
        int j = p * 1024 + t;
        int ww = j >> 6; u64 bit = 1ull << (j & 63);
        if (!((s_enq[ww] >> (j & 63)) & 1ull)) {
            int rk = 0;
            for (int k2 = 0; k2 < ww; ++k2) rk += __popcll(~s_enq[k2]);
            rk += __popcll(~s_enq[ww] & (bit - 1ull));
            int slot = s_base + rk;
            s_pos[j] = (u16)slot;
            s_porder[slot] = j;
        }
    }
    __syncthreads();
    for (int p = 0; p < 2; ++p) {
        int j = p * 1024 + t;
        int fl = s_pos[j];
        if ((s_root[j >> 6] >> (j & 63)) & 1ull) fl |= 0x8000;
        if ((s_enq[j >> 6]  >> (j & 63)) & 1ull) fl |= 0x4000;
        posr[j] = (u16)fl;
        porderW[j] = (u16)s_porder[j];
    }
    if (t == 0) *nrPtr = s_nr;
}

// ---------------------------------------------------------------------------
// K3: bit-transpose heBits -> heT
// ---------------------------------------------------------------------------
__global__ __launch_bounds__(64) void transpose_kernel(
    const u64* __restrict__ heBits, u64* __restrict__ heT)
{
    const int ti = blockIdx.x >> 5;
    const int tj = blockIdx.x & 31;
    const int r = threadIdx.x;
    u64 w = heBits[(size_t)(64 * ti + r) * NW + tj];
    u64 out = 0;
    #pragma unroll
    for (int b = 0; b < 64; ++b) {
        u64 m = __ballot(((w >> b) & 1ull) != 0);
        if (b == r) out = m;
    }
    heT[(size_t)(64 * tj + r) * NW + ti] = out;
}

// ---------------------------------------------------------------------------
// K4: permuted strict-lower parent matrix
// ---------------------------------------------------------------------------
__global__ __launch_bounds__(256) void apbuild_kernel(
    const u64* __restrict__ heT, const u16* __restrict__ porderW,
    const int* __restrict__ nrPtr, u64* __restrict__ Ap)
{
    __shared__ u64 s_row[NW];
    __shared__ u16 s_inv[NN];
    __shared__ int s_invb, s_nr;
    const int b = blockIdx.x;
    const int t = threadIdx.x;
    for (int q = t; q < NN; q += 256) s_inv[q] = porderW[q];
    if (t == 0) { s_invb = porderW[b]; s_nr = *nrPtr; }
    __syncthreads();
    if (t < NW) s_row[t] = heT[(size_t)s_invb * NW + t];
    __syncthreads();
    const bool bge = (b >= s_nr);
    for (int pass = 0; pass < 8; ++pass) {
        int a = pass * 256 + t;
        int ia = s_inv[a];
        bool bit = bge && (a < b) &&
                   (((s_row[ia >> 6] >> (ia & 63)) & 1ull) != 0);
        u64 m = __ballot(bit);
        if ((t & 63) == 0) Ap[(size_t)b * NW + (a >> 6)] = m;
    }
}

// ---------------------------------------------------------------------------
// K5 (fused diag+ap2): block (i,j), j<=i.
//   local Di = closure(Ap_ii) (6 squarings, Ap_ii is never modified);
//   j==i: store Di;  j<i: Ap_ij := Di * Ap_ij  (premultiply in place)
// ---------------------------------------------------------------------------
__global__ __launch_bounds__(64) void diagap2_kernel(
    u64* __restrict__ Ap, u64* __restrict__ Di)
{
    const int i = blockIdx.x;
    const int j = blockIdx.y;
    if (j > i) return;
    __shared__ u64 sm[64];
    const int r = threadIdx.x;
    u64 M = Ap[(size_t)(64 * i + r) * NW + i] | (1ull << r);
    for (int s = 0; s < 6; ++s) {
        sm[r] = M;
        __syncthreads();
        u64 acc = 0;
        #pragma unroll
        for (int b = 0; b < 64; ++b)
            acc |= sm[b] & (0ull - ((M >> b) & 1ull));
        __syncthreads();
        M = acc;
    }
    if (j == i) { Di[64 * i + r] = M; return; }
    sm[r] = Ap[(size_t)(64 * i + r) * NW + j];
    __syncthreads();
    u64 acc = 0;
    #pragma unroll
    for (int b = 0; b < 64; ++b)
        acc |= sm[b] & (0ull - ((M >> b) & 1ull));
    Ap[(size_t)(64 * i + r) * NW + j] = acc;
}

// ---------------------------------------------------------------------------
// K6: half-triangle forward-substitution closure (unchanged — proven).
// ---------------------------------------------------------------------------
__global__ __launch_bounds__(1024) void colhalf_kernel(
    const u64* __restrict__ Ap, const u64* __restrict__ Di,
    u64* __restrict__ Anc)
{
    __shared__ __align__(16) u64 colA[16][64];
    __shared__ u64 part[16][64];
    const int t  = threadIdx.x;
    const int r  = t & 63;
    const int wv = t >> 6;
    const int k    = blockIdx.x & 15;
    const int hb   = blockIdx.x >> 4;
    const int base = hb << 4;
    const int bend = base + 16;
    const int kk   = base + k;

    for (int row = t; row < 64 * kk; row += 1024)
        Anc[(size_t)row * NW + kk] = 0ull;

    if (t < 64) {
        u64 d = Di[64 * kk + r];
        colA[0][r] = d;
        Anc[(size_t)(64 * kk + r) * NW + kk] = d;
    }
    __syncthreads();

    const int j0 = kk + wv;

    for (int ib = kk + 1; ib < bend; ib += 4) {
        u64 m0[4], acc[4];
        #pragma unroll
        for (int g = 0; g < 4; ++g) {
            int ig = ib + g;
            bool v = (ig < bend);
            m0[g] = (v && (j0 < ib)) ? Ap[(size_t)(64 * ig + r) * NW + j0] : 0ull;
            acc[g] = 0ull;
        }
        u64 tm[3][3];
        #pragma unroll
        for (int s = 0; s < 3; ++s) {
            #pragma unroll
            for (int q = 0; q < 3; ++q) {
                int g = s + 1 + q;
                tm[s][q] = (g < 4 && (ib + g) < bend)
                    ? Ap[(size_t)(64 * (ib + g) + r) * NW + (ib + s)] : 0ull;
            }
        }

        if (j0 < ib) {
            const ulonglong2* rp = (const ulonglong2*)&colA[j0 - kk][0];
            #pragma unroll
            for (int bp = 0; bp < 32; ++bp) {
                ulonglong2 ww = rp[bp];
                #pragma unroll
                for (int g = 0; g < 4; ++g)
                    acc[g] = orsel2(acc[g], ww.x, ww.y, m0[g], 2 * bp);
            }
        }

        #pragma unroll
        for (int s = 0; s < 4; ++s) {
            const int i = ib + s;
            if (i < bend) {
                part[wv][r] = acc[s];
                __syncthreads();
                if (wv < 2) {
                    u64 red = part[0][r];
                    #pragma unroll
                    for (int p = 1; p < 16; ++p) red |= part[p][r];
                    if (wv == 0) colA[i - kk][r] = red;
                    else Anc[(size_t)(64 * i + r) * NW + kk] = red;
                }
                __syncthreads();
                if (s < 3 && (i + 1) < bend) {
                    const u64* rowp = colA[i - kk];
                    #pragma unroll
                    for (int bi = 0; bi < 4; ++bi) {
                        int b = 4 * wv + bi;
                        u64 w = rowp[b];
                        u32 wl = (u32)w, wh = (u32)(w >> 32);
                        #pragma unroll
                        for (int q = 0; q < 3; ++q) {
                            int g = s + 1 + q;
                            if (g < 4) {
                                u32 sm2 = (u32)(0u - (u32)((tm[s][q] >> b) & 1ull));
                                u32 al = (u32)acc[g] | (wl & sm2);
                                u32 ah = (u32)(acc[g] >> 32) | (wh & sm2);
                                acc[g] = ((u64)ah << 32) | al;
                            }
                        }
                    }
                }
            }
        }
    }
}

// ---------------------------------------------------------------------------
// K6b: boolean matmul (unchanged — proven round 7, no atomics).
// ---------------------------------------------------------------------------
__global__ __launch_bounds__(256) void merge_kernel(
    const u64* __restrict__ Pb, int pstr,
    const u64* __restrict__ Qb, int qstr,
    u64* __restrict__ Ob, int ostr)
{
    __shared__ u64 SQ[256][17];
    __shared__ u64 PL[16][16];
    const int t    = threadIdx.x;
    const int lane = t & 63;
    const int wv   = t >> 6;
    const int grp  = (lane >> 4);
    const int w    = lane & 15;
    const int rb   = blockIdx.x;

    PL[t >> 4][t & 15] = Pb[(size_t)(16 * rb + (t >> 4)) * pstr + (t & 15)];

    u64 acc0 = 0, acc1 = 0, acc2 = 0, acc3 = 0;

    for (int cs = 0; cs < 4; ++cs) {
        __syncthreads();
        for (int q = t; q < 4096; q += 256)
            SQ[q >> 4][q & 15] = Qb[(size_t)(256 * cs + (q >> 4)) * qstr + (q & 15)];
        __syncthreads();
        #pragma unroll
        for (int cw = 0; cw < 4; ++cw) {
            u64 m0 = PL[4 * wv + 0][cs * 4 + cw];
            u64 m1 = PL[4 * wv + 1][cs * 4 + cw];
            u64 m2 = PL[4 * wv + 2][cs * 4 + cw];
            u64 m3 = PL[4 * wv + 3][cs * 4 + cw];
            #pragma unroll
            for (int cc = 0; cc < 16; ++cc) {
                u64 qq = SQ[cw * 64 + cc * 4 + grp][w];
                int sh = (cc & 7) * 4 + grp;
                u32 h0 = (cc < 8) ? (u32)m0 : (u32)(m0 >> 32);
                u32 h1 = (cc < 8) ? (u32)m1 : (u32)(m1 >> 32);
                u32 h2 = (cc < 8) ? (u32)m2 : (u32)(m2 >> 32);
                u32 h3 = (cc < 8) ? (u32)m3 : (u32)(m3 >> 32);
                u32 ql = (u32)qq, qh = (u32)(qq >> 32);
                u32 s;
                s = SBFE(h0, sh);
                acc0 = ((u64)(((u32)(acc0 >> 32)) | (qh & s)) << 32) | (((u32)acc0) | (ql & s));
                s = SBFE(h1, sh);
                acc1 = ((u64)(((u32)(acc1 >> 32)) | (qh & s)) << 32) | (((u32)acc1) | (ql & s));
                s = SBFE(h2, sh);
                acc2 = ((u64)(((u32)(acc2 >> 32)) | (qh & s)) << 32) | (((u32)acc2) | (ql & s));
                s = SBFE(h3, sh);
                acc3 = ((u64)(((u32)(acc3 >> 32)) | (qh & s)) << 32) | (((u32)acc3) | (ql & s));
            }
        }
    }

    acc0 |= __shfl_xor(acc0, 16); acc0 |= __shfl_xor(acc0, 32);
    acc1 |= __shfl_xor(acc1, 16); acc1 |= __shfl_xor(acc1, 32);
    acc2 |= __shfl_xor(acc2, 16); acc2 |= __shfl_xor(acc2, 32);
    acc3 |= __shfl_xor(acc3, 16); acc3 |= __shfl_xor(acc3, 32);

    if (grp == 0) {
        size_t base = (size_t)(16 * rb + 4 * wv) * ostr + w;
        Ob[base] = acc0;
        Ob[base + ostr] = acc1;
        Ob[base + 2 * (size_t)ostr] = acc2;
        Ob[base + 3 * (size_t)ostr] = acc3;
    }
}

// ---------------------------------------------------------------------------
// K7 (fused fold+out): dag[i][j] = he & !root_j & !anc & reach_i, as floats.
// ---------------------------------------------------------------------------
__global__ __launch_bounds__(256) void foldout_kernel(
    const u64* __restrict__ heBits,
    const u64* __restrict__ Anc,
    const u16* __restrict__ posr,
    float* __restrict__ dag)
{
    __shared__ u64 s_anc[NW];
    __shared__ u64 s_he[NW];
    __shared__ u16 s_pr[NN];
    const int i = blockIdx.x;
    const int t = threadIdx.x;

    ((int4*)s_pr)[t] = ((const int4*)posr)[t];
    __syncthreads();
    const int fl = s_pr[i];
    const int pi = fl & 0x7FF;
    if (t < NW) {
        s_anc[t] = Anc[(size_t)pi * NW + t];
        s_he[t]  = heBits[(size_t)i * NW + t];
    }
    __syncthreads();
    const bool reach_i = (fl & 0x4000) != 0;
    const int j0 = t * 8;
    float o[8];
    #pragma unroll
    for (int e = 0; e < 8; ++e) {
        int j = j0 + e;
        int pr = s_pr[j];
        int a = pr & 0x7FF;
        bool he = ((s_he[j >> 6] >> (j & 63)) & 1ull) != 0;
        bool anc = ((s_anc[a >> 6] >> (a & 63)) & 1ull) != 0;
        o[e] = (reach_i && he && ((pr & 0x8000) == 0) && !anc) ? 1.f : 0.f;
    }
    float4* outp = (float4*)(dag + (size_t)i * NN + j0);
    outp[0] = make_float4(o[0], o[1], o[2], o[3]);
    outp[1] = make_float4(o[4], o[5], o[6], o[7]);
}

// ---------------------------------------------------------------------------
extern "C" void kernel_launch(void* const* d_in, const int* in_sizes, int n_in,
                              void* d_out, int out_size, void* d_ws, size_t ws_size,
                              hipStream_t stream) {
    const float* root_logits = (const float*)d_in[0];
    const float* edge_logits = (const float*)d_in[1];
    const float* g_root      = (const float*)d_in[2];
    const float* g_edge      = (const float*)d_in[3];
    float* dag = (float*)d_out;

    // all scratch in d_ws (~2.2 MB; ws is 256 MiB per the poison-fill size)
    char* ws = (char*)d_ws;
    u64* heBits  = (u64*)(ws);                           // 512 KB
    u64* heT     = (u64*)(ws + (512 << 10));             // 512 KB
    u64* Ap      = (u64*)(ws + (1 << 20));               // 512 KB
    u64* Anc     = (u64*)(ws + (1 << 20) + (512 << 10)); // 512 KB
    u64* Di      = (u64*)(ws + (2 << 20));               //  16 KB
    u64* M1      = (u64*)(ws + (2 << 20) + (16 << 10));  // 128 KB
    u16* posr    = (u16*)(ws + (2 << 20) + (160 << 10)); //   4 KB
    u16* porderW = (u16*)(ws + (2 << 20) + (164 << 10)); //   4 KB
    int* nrPtr   = (int*)(ws + (2 << 20) + (168 << 10)); //   4 B

    prep_kernel     <<<NN, 256, 0, stream>>>(edge_logits, g_edge, heBits);
    order_kernel    <<<1, 1024, 0, stream>>>(root_logits, g_root, heBits,
                                             posr, porderW, nrPtr);
    transpose_kernel<<<NN / 2, 64, 0, stream>>>(heBits, heT);
    apbuild_kernel  <<<NN, 256, 0, stream>>>(heT, porderW, nrPtr, Ap);
    diagap2_kernel  <<<dim3(NW, NW), 64, 0, stream>>>(Ap, Di);
    colhalf_kernel  <<<NW, 1024, 0, stream>>>(Ap, Di, Anc);
    // M1 = C' * A*   (C' rows = Ap B-rows words 0..15; A* = Anc T-rows)
    merge_kernel<<<64, 256, 0, stream>>>(Ap + (size_t)1024 * NW, NW,
                                         Anc, NW, M1, 16);
    // Anc[B, T-words] = B* * M1   (B* = Anc B-rows words 16..31)
    merge_kernel<<<64, 256, 0, stream>>>(Anc + (size_t)1024 * NW + 16, NW,
                                         M1, 16,
                                         Anc + (size_t)1024 * NW, NW);
    foldout_kernel  <<<NN, 256, 0, stream>>>(heBits, Anc, posr, dag);
}